// Round 1
// baseline (320.727 us; speedup 1.0000x reference)
//
#include <hip/hip_runtime.h>
#include <hip/hip_bf16.h>
#include <stdint.h>

// Problem constants
#define BT     32768      // B*T rows
#define CIN    512
#define NE     640        // GROUP*ENTRY
#define ENTRY  320
#define DD     256        // COUT/GROUP
#define MROWS  32         // rows per block
#define TPB    256        // 4 waves

using bf16x8 = __attribute__((ext_vector_type(8))) short;
using f32x4  = __attribute__((ext_vector_type(4))) float;

// LDS layout (bytes):
//   phase 1 : xA bf16 [32 rows][512]  -> [0, 32768), XOR-swizzled 16B slots
//   phase2/3: y  bf16 [32 rows][640]  -> [0, 40960), XOR-swizzled (unions with xA)
//   always  : S  f32  [32]            -> [40960, 41088)
// 41088 B/block -> 3 blocks/CU (123.3 KB < 160 KB), 12 waves/CU.
#define S_OFF      40960
#define SMEM_BYTES 41088

__device__ __forceinline__ unsigned short f2b(float f) {
    union { float f; uint32_t u; } v; v.f = f;
    uint32_t u = v.u;
    return (unsigned short)((u + 0x7FFFu + ((u >> 16) & 1u)) >> 16);
}

// Prep: Wp (fp32 [640,512]) -> WpB (bf16 [e][k]), codebooks (fp32 [2,320,256]) -> cbT (bf16 [2,256,320])
__global__ void prep_kernel(const float* __restrict__ Wp, const float* __restrict__ cb,
                            unsigned short* __restrict__ WpB, unsigned short* __restrict__ cbT) {
    int i = blockIdx.x * blockDim.x + threadIdx.x;
    if (i < NE * CIN) {
        WpB[i] = f2b(Wp[i]);
    } else {
        int o = i - NE * CIN;
        if (o < 2 * ENTRY * DD) {
            int g = o / (DD * ENTRY);
            int r = o - g * (DD * ENTRY);
            int d = r / ENTRY;
            int e = r - d * ENTRY;
            cbT[o] = f2b(cb[(g * ENTRY + e) * DD + d]);
        }
    }
}

__global__ __launch_bounds__(TPB, 3) void fused_kernel(
    const float* __restrict__ x, const float* __restrict__ bp,
    const float* __restrict__ gum, const unsigned short* __restrict__ WpB,
    const unsigned short* __restrict__ cbT, float* __restrict__ out) {

    extern __shared__ char smem[];
    float* sS = (float*)(smem + S_OFF);

    const int tid = threadIdx.x;
    const int w  = tid >> 6;     // wave 0..3
    const int l  = tid & 63;     // lane
    const int q  = l >> 4;       // quad 0..3
    const int ln = l & 15;
    const int rowbase = blockIdx.x * MROWS;
    const int swz = (ln & 7) << 4;   // A-row swizzle (row&7 == ln&7 for rows ln and 16+ln)

    if (tid < MROWS) sS[tid] = 0.0f;

    // ---------------- Phase 0: stage x -> bf16 LDS (once, swizzled) ----------------
    {
        const int ar  = tid >> 3;   // row 0..31
        const int akq = tid & 7;    // 4-float quarter within 32-elem chunk
        const float* xrow = x + (size_t)(rowbase + ar) * CIN + akq * 4;
        const int abase = ar * 1024;
        const int aswz  = (ar & 7) << 4;
#pragma unroll
        for (int ks = 0; ks < 16; ++ks) {
            float4 xv = *(const float4*)(xrow + ks * 32);
            ushort4 hv;
            hv.x = f2b(xv.x); hv.y = f2b(xv.y); hv.z = f2b(xv.z); hv.w = f2b(xv.w);
            *(ushort4*)(smem + abase + ((ks * 64 + akq * 8) ^ aswz)) = hv;
        }
    }
    __syncthreads();

    // ---------------- Phase 1: logits = x @ Wp^T (no barriers, B direct from L2) ----------------
    f32x4 acc1[2][10];
    const f32x4 fz = {0.f, 0.f, 0.f, 0.f};
#pragma unroll
    for (int rt = 0; rt < 2; ++rt)
#pragma unroll
        for (int ct = 0; ct < 10; ++ct) acc1[rt][ct] = fz;

    int boff[10];
#pragma unroll
    for (int ct = 0; ct < 10; ++ct)
        boff[ct] = (w * 160 + ct * 16 + ln) * CIN + q * 8;

#pragma unroll 2
    for (int ks = 0; ks < 16; ++ks) {
        const unsigned short* Bk = WpB + ks * 32;   // uniform base (SGPR) + lane offset
        bf16x8 bfr[10];
#pragma unroll
        for (int ct = 0; ct < 10; ++ct)
            bfr[ct] = *(const bf16x8*)(Bk + boff[ct]);
        const int at = (ks * 64 + q * 16) ^ swz;
        bf16x8 af0 = *(const bf16x8*)(smem + ln * 1024 + at);
        bf16x8 af1 = *(const bf16x8*)(smem + ln * 1024 + 16384 + at);
#pragma unroll
        for (int ct = 0; ct < 10; ++ct) {
            acc1[0][ct] = __builtin_amdgcn_mfma_f32_16x16x32_bf16(af0, bfr[ct], acc1[0][ct], 0, 0, 0);
            acc1[1][ct] = __builtin_amdgcn_mfma_f32_16x16x32_bf16(af1, bfr[ct], acc1[1][ct], 0, 0, 0);
        }
    }
    __syncthreads();   // xA dead; y region reuses it

    // ---------------- Phase 2: exp + row sums; y -> LDS (swizzled) ----------------
    float bpv[10];
#pragma unroll
    for (int ct = 0; ct < 10; ++ct) bpv[ct] = bp[w * 160 + ct * 16 + ln];

    const float* gbase = gum + (size_t)rowbase * NE + w * 160 + ln;
    float gv[10];
    {
        const float* p0 = gbase + (size_t)(q * 4) * NE;   // ri=0 -> row q*4
#pragma unroll
        for (int ct = 0; ct < 10; ++ct) gv[ct] = p0[ct * 16];
    }
#pragma unroll
    for (int ri = 0; ri < 8; ++ri) {
        float gn[10];
        if (ri < 7) {
            int nrow = ((ri + 1) >> 2) * 16 + q * 4 + ((ri + 1) & 3);
            const float* pn = gbase + (size_t)nrow * NE;
#pragma unroll
            for (int ct = 0; ct < 10; ++ct) gn[ct] = pn[ct * 16];
        }
        int rt = ri >> 2, r = ri & 3;
        int row = rt * 16 + q * 4 + r;
        int ybase = row * 1280;
        int yswz  = (row & 7) << 4;
        float p = 0.f;
#pragma unroll
        for (int ct = 0; ct < 10; ++ct) {
            int col = w * 160 + ct * 16 + ln;
            float v = acc1[rt][ct][r] + bpv[ct] + gv[ct];
            float e = __expf(v);
            *(unsigned short*)(smem + ybase + ((col * 2) ^ yswz)) = f2b(e);
            p += e;
        }
        p += __shfl_xor(p, 1);
        p += __shfl_xor(p, 2);
        p += __shfl_xor(p, 4);
        p += __shfl_xor(p, 8);
        if (ln == 0) atomicAdd(&sS[row], p);
#pragma unroll
        for (int ct = 0; ct < 10; ++ct) gv[ct] = gn[ct];
    }
    __syncthreads();   // y + S complete before phase 3 reads

    // ---------------- Phase 3: out = (y @ cb) / S (no barriers, B direct from L2) ----------------
    f32x4 acc2[2][8];
#pragma unroll
    for (int rt = 0; rt < 2; ++rt)
#pragma unroll
        for (int ct = 0; ct < 8; ++ct) acc2[rt][ct] = fz;

    const int g  = w >> 1;          // group
    const int nb = (w & 1) * 128;   // col block within group

    int coff[8];
#pragma unroll
    for (int ct = 0; ct < 8; ++ct)
        coff[ct] = (g * DD + nb + ct * 16 + ln) * ENTRY + q * 8;

#pragma unroll 2
    for (int ks = 0; ks < 10; ++ks) {
        const unsigned short* Ck = cbT + ks * 32;   // uniform base + lane offset
        bf16x8 bfr[8];
#pragma unroll
        for (int ct = 0; ct < 8; ++ct)
            bfr[ct] = *(const bf16x8*)(Ck + coff[ct]);
        const int at = (g * 640 + ks * 64 + q * 16) ^ swz;
        bf16x8 af0 = *(const bf16x8*)(smem + ln * 1280 + at);
        bf16x8 af1 = *(const bf16x8*)(smem + ln * 1280 + 20480 + at);
#pragma unroll
        for (int ct = 0; ct < 8; ++ct) {
            acc2[0][ct] = __builtin_amdgcn_mfma_f32_16x16x32_bf16(af0, bfr[ct], acc2[0][ct], 0, 0, 0);
            acc2[1][ct] = __builtin_amdgcn_mfma_f32_16x16x32_bf16(af1, bfr[ct], acc2[1][ct], 0, 0, 0);
        }
    }

    // epilogue: divide by softmax denom, store fp32
#pragma unroll
    for (int rt = 0; rt < 2; ++rt) {
#pragma unroll
        for (int r = 0; r < 4; ++r) {
            int row = rt * 16 + q * 4 + r;
            float inv = 1.0f / sS[row];
            size_t orow = (size_t)(rowbase + row) * 512;
#pragma unroll
            for (int ct = 0; ct < 8; ++ct) {
                int col = g * DD + nb + ct * 16 + ln;
                out[orow + col] = acc2[rt][ct][r] * inv;
            }
        }
    }
}

extern "C" void kernel_launch(void* const* d_in, const int* in_sizes, int n_in,
                              void* d_out, int out_size, void* d_ws, size_t ws_size,
                              hipStream_t stream) {
    const float* x   = (const float*)d_in[0];
    const float* Wp  = (const float*)d_in[1];
    const float* bp  = (const float*)d_in[2];
    const float* cb  = (const float*)d_in[3];
    const float* gum = (const float*)d_in[4];
    float* out = (float*)d_out;

    unsigned short* WpB = (unsigned short*)d_ws;
    unsigned short* cbT = WpB + NE * CIN;

    int prep_total = NE * CIN + 2 * ENTRY * DD;
    prep_kernel<<<(prep_total + 255) / 256, 256, 0, stream>>>(Wp, cb, WpB, cbT);

    fused_kernel<<<dim3(BT / MROWS), dim3(TPB), SMEM_BYTES, stream>>>(x, bp, gum, WpB, cbT, out);
}

// Round 2
// 282.600 us; speedup vs baseline: 1.1349x; 1.1349x over previous
//
#include <hip/hip_runtime.h>
#include <hip/hip_bf16.h>
#include <stdint.h>

// Problem constants
#define BT     32768      // B*T rows
#define CIN    512
#define NE     640        // GROUP*ENTRY
#define ENTRY  320
#define DD     256        // COUT/GROUP
#define MROWS  64         // rows per block
#define TPB    512        // 8 waves

using bf16x8 = __attribute__((ext_vector_type(8))) short;
using f32x4  = __attribute__((ext_vector_type(4))) float;

// LDS layout (bytes):
//   A  bf16 [64 rows][512], XOR-swizzled      : [0, 65536)        phase 0/1
//   B  dbuf 2 x 40960, k-major (q*10240+e*16) : [65536, 147456)   phase 1
//   y  bf16 [64 rows][640], XOR-swizzled      : [0, 81920)        phase 2/3 (unions A + B0 head)
//   cb dbuf 2 x 32768, k-major (q*8192+n*16)  : [81920, 147456)   phase 2(prefetch)/3
//   S  f32 [64]                               : [147456, 147712)
// 147712 B -> 1 block/CU (8 waves), like the verified m201 shape.
#define B_OFF   65536
#define B_BUF   40960
#define CB_OFF  81920
#define CB_BUF  32768
#define S_OFF   147456
#define SMEM_BYTES 147712

__device__ __forceinline__ unsigned short f2b(float f) {
    union { float f; uint32_t u; } v; v.f = f;
    uint32_t u = v.u;
    return (unsigned short)((u + 0x7FFFu + ((u >> 16) & 1u)) >> 16);
}

__device__ __forceinline__ void gl2lds16(const void* g, void* l) {
    __builtin_amdgcn_global_load_lds((const __attribute__((address_space(1))) void*)g,
                                     (__attribute__((address_space(3))) void*)l, 16, 0, 0);
}

// Prep: Wp (fp32 [640,512]) -> WpB (bf16 [e][k]), codebooks (fp32 [2,320,256]) -> cbT (bf16 [2,256,320])
__global__ void prep_kernel(const float* __restrict__ Wp, const float* __restrict__ cb,
                            unsigned short* __restrict__ WpB, unsigned short* __restrict__ cbT) {
    int i = blockIdx.x * blockDim.x + threadIdx.x;
    if (i < NE * CIN) {
        WpB[i] = f2b(Wp[i]);
    } else {
        int o = i - NE * CIN;
        if (o < 2 * ENTRY * DD) {
            int g = o / (DD * ENTRY);
            int r = o - g * (DD * ENTRY);
            int d = r / ENTRY;
            int e = r - d * ENTRY;
            cbT[o] = f2b(cb[(g * ENTRY + e) * DD + d]);
        }
    }
}

__global__ __launch_bounds__(TPB, 2) void fused_kernel(
    const float* __restrict__ x, const float* __restrict__ bpv_g,
    const float* __restrict__ gum, const unsigned short* __restrict__ WpB,
    const unsigned short* __restrict__ cbT, float* __restrict__ out) {

    extern __shared__ char smem[];
    float* sS = (float*)(smem + S_OFF);

    const int tid = threadIdx.x;
    const int w  = tid >> 6;     // wave 0..7
    const int l  = tid & 63;
    const int q  = l >> 4;       // quad 0..3
    const int ln = l & 15;
    const int wr = w >> 2;       // wave-row 0..1 (32 rows each)
    const int wc = w & 3;        // wave-col 0..3
    const int rowbase = blockIdx.x * MROWS;
    const int swz = (ln & 7) << 4;

    // Pre-permuted global source offsets (element units) for k-major LDS staging (rule 21):
    // B chunk s in [0,2560): q=s/640, e=s%640 ; lds slot s*16 = q*10240 + e*16
    int bgo[5];
#pragma unroll
    for (int i = 0; i < 5; ++i) {
        int s = i * TPB + tid;
        int qq = s / 640, e = s - qq * 640;
        bgo[i] = e * CIN + qq * 8;
    }
    // cb chunk s in [0,2048): q=s>>9, n=s&511 ; lds slot s*16 = q*8192 + n*16
    int cgo[4];
#pragma unroll
    for (int i = 0; i < 4; ++i) {
        int s = i * TPB + tid;
        int qq = s >> 9, n = s & 511;
        cgo[i] = n * ENTRY + qq * 8;
    }

    if (tid < MROWS) sS[tid] = 0.0f;

    // Issue B buf0 (ks=0) DMA immediately — overlaps with phase-0 x conversion.
#pragma unroll
    for (int i = 0; i < 5; ++i)
        gl2lds16(WpB + bgo[i], smem + B_OFF + (i * TPB + tid) * 16);

    // ---------------- Phase 0: stage x -> bf16 LDS (once, swizzled) ----------------
    {
        const int ar  = tid >> 3;   // row 0..63
        const int akq = tid & 7;
        const float* xrow = x + (size_t)(rowbase + ar) * CIN + akq * 4;
        const int abase = ar * 1024;
        const int aswz  = (ar & 7) << 4;
#pragma unroll
        for (int c = 0; c < 16; ++c) {
            float4 xv = *(const float4*)(xrow + c * 32);
            ushort4 hv;
            hv.x = f2b(xv.x); hv.y = f2b(xv.y); hv.z = f2b(xv.z); hv.w = f2b(xv.w);
            *(ushort4*)(smem + abase + ((c * 64 + akq * 8) ^ aswz)) = hv;
        }
    }
    __syncthreads();   // drains vmcnt(0): A ready AND B buf0 ready

    // ---------------- Phase 1: logits = x @ Wp^T (dbuf DMA, counted vmcnt) ----------------
    f32x4 acc1[2][10];
    const f32x4 fz = {0.f, 0.f, 0.f, 0.f};
#pragma unroll
    for (int rt = 0; rt < 2; ++rt)
#pragma unroll
        for (int ct = 0; ct < 10; ++ct) acc1[rt][ct] = fz;

    const int aB = (wr * 32 + ln) * 1024;                  // + rt*16384
    const int bB = q * 10240 + (wc * 160 + ln) * 16;       // within a B buffer

#pragma unroll 2
    for (int ks = 0; ks < 16; ++ks) {
        const int cur = ks & 1;
        if (ks < 15) {
            const unsigned short* gk = WpB + (ks + 1) * 32;
            char* lb = smem + B_OFF + (cur ^ 1) * B_BUF;
#pragma unroll
            for (int i = 0; i < 5; ++i)
                gl2lds16(gk + bgo[i], lb + (i * TPB + tid) * 16);
            asm volatile("s_waitcnt vmcnt(5)" ::: "memory");   // buf[cur]'s 5 landed; 5 stay in flight
        } else {
            asm volatile("s_waitcnt vmcnt(0)" ::: "memory");
        }
        asm volatile("s_barrier" ::: "memory");                // buf[cur] visible to all waves

        const int at = (ks * 64 + q * 16) ^ swz;
        bf16x8 af0 = *(const bf16x8*)(smem + aB + at);
        bf16x8 af1 = *(const bf16x8*)(smem + aB + 16384 + at);
        bf16x8 bfr[10];
        const char* bsrc = smem + B_OFF + cur * B_BUF + bB;
#pragma unroll
        for (int ct = 0; ct < 10; ++ct)
            bfr[ct] = *(const bf16x8*)(bsrc + ct * 256);
        asm volatile("s_waitcnt lgkmcnt(0)" ::: "memory");
        __builtin_amdgcn_sched_barrier(0);
        asm volatile("s_barrier" ::: "memory");                // reads done -> buf[cur] reusable

        __builtin_amdgcn_s_setprio(1);
#pragma unroll
        for (int ct = 0; ct < 10; ++ct) {
            acc1[0][ct] = __builtin_amdgcn_mfma_f32_16x16x32_bf16(af0, bfr[ct], acc1[0][ct], 0, 0, 0);
            acc1[1][ct] = __builtin_amdgcn_mfma_f32_16x16x32_bf16(af1, bfr[ct], acc1[1][ct], 0, 0, 0);
        }
        __builtin_amdgcn_s_setprio(0);
    }
    __syncthreads();   // phase-1 LDS fully dead

    // Prefetch cb buf0 DMA now — overlaps with all of phase 2. (cb region doesn't overlap y.)
#pragma unroll
    for (int i = 0; i < 4; ++i)
        gl2lds16(cbT + cgo[i], smem + CB_OFF + (i * TPB + tid) * 16);

    // ---------------- Phase 2: exp + row sums; y -> LDS (swizzled) ----------------
    float bpv[10];
#pragma unroll
    for (int ct = 0; ct < 10; ++ct) bpv[ct] = bpv_g[wc * 160 + ct * 16 + ln];

    const float* gbase = gum + (size_t)(rowbase + wr * 32) * NE + wc * 160 + ln;
    float gv[10];
    {
        const float* p0 = gbase + (size_t)(q * 4) * NE;
#pragma unroll
        for (int ct = 0; ct < 10; ++ct) gv[ct] = p0[ct * 16];
    }
#pragma unroll
    for (int ri = 0; ri < 8; ++ri) {
        float gn[10];
        if (ri < 7) {
            int nrow = ((ri + 1) >> 2) * 16 + q * 4 + ((ri + 1) & 3);
            const float* pn = gbase + (size_t)nrow * NE;
#pragma unroll
            for (int ct = 0; ct < 10; ++ct) gn[ct] = pn[ct * 16];
        }
        int rt = ri >> 2, r = ri & 3;
        int lrow = wr * 32 + rt * 16 + q * 4 + r;
        int ybase = lrow * 1280;
        int yswz  = (lrow & 7) << 4;
        float p = 0.f;
#pragma unroll
        for (int ct = 0; ct < 10; ++ct) {
            int col = wc * 160 + ct * 16 + ln;
            float v = acc1[rt][ct][r] + bpv[ct] + gv[ct];
            float e = __expf(v);
            *(unsigned short*)(smem + ybase + ((col * 2) ^ yswz)) = f2b(e);
            p += e;
        }
        p += __shfl_xor(p, 1);
        p += __shfl_xor(p, 2);
        p += __shfl_xor(p, 4);
        p += __shfl_xor(p, 8);
        if (ln == 0) atomicAdd(&sS[lrow], p);
#pragma unroll
        for (int ct = 0; ct < 10; ++ct) gv[ct] = gn[ct];
    }
    __syncthreads();   // y + S complete; cb buf0 DMA also drained here

    // ---------------- Phase 3: out = (y @ cb) / S (dbuf DMA, counted vmcnt) ----------------
    f32x4 acc2[2][8];
#pragma unroll
    for (int rt = 0; rt < 2; ++rt)
#pragma unroll
        for (int ct = 0; ct < 8; ++ct) acc2[rt][ct] = fz;

    const int g  = wc >> 1;          // group
    const int nb = (wc & 1) * 128;   // col block within group
    const int yB = (wr * 32 + ln) * 1280;                    // + rt*20480
    const int cB = q * 8192 + (g * 256 + nb + ln) * 16;      // within a cb buffer

#pragma unroll 2
    for (int ks = 0; ks < 10; ++ks) {
        const int cur = ks & 1;
        if (ks < 9) {
            const unsigned short* gk = cbT + (ks + 1) * 32;
            char* lb = smem + CB_OFF + (cur ^ 1) * CB_BUF;
#pragma unroll
            for (int i = 0; i < 4; ++i)
                gl2lds16(gk + cgo[i], lb + (i * TPB + tid) * 16);
            asm volatile("s_waitcnt vmcnt(4)" ::: "memory");
        } else {
            asm volatile("s_waitcnt vmcnt(0)" ::: "memory");
        }
        asm volatile("s_barrier" ::: "memory");

        const int at = (g * 640 + ks * 64 + q * 16) ^ swz;
        bf16x8 af0 = *(const bf16x8*)(smem + yB + at);
        bf16x8 af1 = *(const bf16x8*)(smem + yB + 20480 + at);
        bf16x8 bfr[8];
        const char* csrc = smem + CB_OFF + cur * CB_BUF + cB;
#pragma unroll
        for (int ct = 0; ct < 8; ++ct)
            bfr[ct] = *(const bf16x8*)(csrc + ct * 256);
        asm volatile("s_waitcnt lgkmcnt(0)" ::: "memory");
        __builtin_amdgcn_sched_barrier(0);
        asm volatile("s_barrier" ::: "memory");

        __builtin_amdgcn_s_setprio(1);
#pragma unroll
        for (int ct = 0; ct < 8; ++ct) {
            acc2[0][ct] = __builtin_amdgcn_mfma_f32_16x16x32_bf16(af0, bfr[ct], acc2[0][ct], 0, 0, 0);
            acc2[1][ct] = __builtin_amdgcn_mfma_f32_16x16x32_bf16(af1, bfr[ct], acc2[1][ct], 0, 0, 0);
        }
        __builtin_amdgcn_s_setprio(0);
    }

    // epilogue: divide by softmax denom, store fp32
#pragma unroll
    for (int rt = 0; rt < 2; ++rt) {
#pragma unroll
        for (int r = 0; r < 4; ++r) {
            int lrow = wr * 32 + rt * 16 + q * 4 + r;
            float inv = 1.0f / sS[lrow];
            size_t orow = (size_t)(rowbase + lrow) * 512;
#pragma unroll
            for (int ct = 0; ct < 8; ++ct) {
                int col = g * 256 + nb + ct * 16 + ln;
                out[orow + col] = acc2[rt][ct][r] * inv;
            }
        }
    }
}

extern "C" void kernel_launch(void* const* d_in, const int* in_sizes, int n_in,
                              void* d_out, int out_size, void* d_ws, size_t ws_size,
                              hipStream_t stream) {
    const float* x   = (const float*)d_in[0];
    const float* Wp  = (const float*)d_in[1];
    const float* bp  = (const float*)d_in[2];
    const float* cb  = (const float*)d_in[3];
    const float* gum = (const float*)d_in[4];
    float* out = (float*)d_out;

    unsigned short* WpB = (unsigned short*)d_ws;
    unsigned short* cbT = WpB + NE * CIN;

    int prep_total = NE * CIN + 2 * ENTRY * DD;
    prep_kernel<<<(prep_total + 255) / 256, 256, 0, stream>>>(Wp, cb, WpB, cbT);

    fused_kernel<<<dim3(BT / MROWS), dim3(TPB), SMEM_BYTES, stream>>>(x, bp, gum, WpB, cbT, out);
}

// Round 3
// 238.491 us; speedup vs baseline: 1.3448x; 1.1850x over previous
//
#include <hip/hip_runtime.h>
#include <hip/hip_bf16.h>
#include <stdint.h>

// Problem constants
#define BT     32768      // B*T rows
#define CIN    512
#define NE     640        // GROUP*ENTRY
#define ENTRY  320
#define DD     256        // COUT/GROUP
#define MROWS  64         // rows per block
#define TPB    512        // 8 waves

using bf16x8 = __attribute__((ext_vector_type(8))) short;
using f32x4  = __attribute__((ext_vector_type(4))) float;

// LDS layout (bytes):
//   A  bf16 [64 rows][512], XOR-swizzled        : [0, 65536)        phase 0/1
//   B  dbuf 2 x 40960, row e*64B, XOR'd quarters: [65536, 147456)   phase 1
//   y  bf16 [64 rows][640], XOR-swizzled        : [0, 81920)        phase 2/3
//   cb dbuf 2 x 32768, row n*64B, XOR'd quarters: [81920, 147456)   phase 3
//   S  f32 [64]                                 : [147456, 147712)
#define B_OFF   65536
#define B_BUF   40960
#define CB_OFF  81920
#define CB_BUF  32768
#define S_OFF   147456
#define SMEM_BYTES 147712

__device__ __forceinline__ unsigned short f2b(float f) {
    union { float f; uint32_t u; } v; v.f = f;
    uint32_t u = v.u;
    return (unsigned short)((u + 0x7FFFu + ((u >> 16) & 1u)) >> 16);
}

__device__ __forceinline__ void gl2lds16(const void* g, void* l) {
    __builtin_amdgcn_global_load_lds((const __attribute__((address_space(1))) void*)g,
                                     (__attribute__((address_space(3))) void*)l, 16, 0, 0);
}

// Prep: Wp (fp32 [640,512]) -> WpB (bf16 [e][k]), codebooks (fp32 [2,320,256]) -> cbT (bf16 [2,256,320])
__global__ void prep_kernel(const float* __restrict__ Wp, const float* __restrict__ cb,
                            unsigned short* __restrict__ WpB, unsigned short* __restrict__ cbT) {
    int i = blockIdx.x * blockDim.x + threadIdx.x;
    if (i < NE * CIN) {
        WpB[i] = f2b(Wp[i]);
    } else {
        int o = i - NE * CIN;
        if (o < 2 * ENTRY * DD) {
            int g = o / (DD * ENTRY);
            int r = o - g * (DD * ENTRY);
            int d = r / ENTRY;
            int e = r - d * ENTRY;
            cbT[o] = f2b(cb[(g * ENTRY + e) * DD + d]);
        }
    }
}

__global__ __launch_bounds__(TPB, 2) void fused_kernel(
    const float* __restrict__ x, const float* __restrict__ bpv_g,
    const float* __restrict__ gum, const unsigned short* __restrict__ WpB,
    const unsigned short* __restrict__ cbT, float* __restrict__ out) {

    extern __shared__ char smem[];
    float* sS = (float*)(smem + S_OFF);

    const int tid = threadIdx.x;
    const int w  = tid >> 6;     // wave 0..7
    const int l  = tid & 63;
    const int q  = l >> 4;       // quad 0..3
    const int ln = l & 15;
    const int wr = w >> 2;       // wave-row 0..1 (32 rows each)
    const int wc = w & 3;        // wave-col 0..3
    const int rowbase = blockIdx.x * MROWS;
    const int swz = (ln & 7) << 4;
    const int qswz = (q ^ ((ln >> 1) & 3)) << 4;   // B/cb fragment quarter swizzle

    // Line-coalesced staging offsets (element units), round-0 mapping:
    // B chunk s in [0,2560): e = s>>2, q2 = (s&3)^((e>>1)&3); src = e*CIN + q2*8
    // -> 4 consecutive lanes cover one contiguous 64B row-slice (full-line requests).
    // LDS: slot s*16 => row e at e*64, quarters XOR-permuted.
    int bgo[5];
#pragma unroll
    for (int i = 0; i < 5; ++i) {
        int s = i * TPB + tid;
        int e = s >> 2, q2 = (s & 3) ^ ((e >> 1) & 3);
        bgo[i] = e * CIN + q2 * 8;
    }
    // cb chunk s in [0,2048): gg = s>>10, n = (s&1023)>>2, q2 = (s&3)^((n>>1)&3);
    // src = (gg*DD + n)*ENTRY + q2*8 ; LDS row (gg*256+n) at *64.
    int cgo[4];
#pragma unroll
    for (int i = 0; i < 4; ++i) {
        int s = i * TPB + tid;
        int gg = s >> 10, n = (s & 1023) >> 2;
        int q2 = (s & 3) ^ ((n >> 1) & 3);
        cgo[i] = (gg * DD + n) * ENTRY + q2 * 8;
    }

    if (tid < MROWS) sS[tid] = 0.0f;

    // Issue B buf0 (ks=0) DMA immediately — overlaps with phase-0 x conversion.
#pragma unroll
    for (int i = 0; i < 5; ++i)
        gl2lds16(WpB + bgo[i], smem + B_OFF + (i * TPB + tid) * 16);

    // ---------------- Phase 0: stage x -> bf16 LDS (once, swizzled) ----------------
    {
        const int ar  = tid >> 3;   // row 0..63
        const int akq = tid & 7;
        const float* xrow = x + (size_t)(rowbase + ar) * CIN + akq * 4;
        const int abase = ar * 1024;
        const int aswz  = (ar & 7) << 4;
#pragma unroll
        for (int c = 0; c < 16; ++c) {
            float4 xv = *(const float4*)(xrow + c * 32);
            ushort4 hv;
            hv.x = f2b(xv.x); hv.y = f2b(xv.y); hv.z = f2b(xv.z); hv.w = f2b(xv.w);
            *(ushort4*)(smem + abase + ((c * 64 + akq * 8) ^ aswz)) = hv;
        }
    }
    __syncthreads();   // drains vmcnt(0): A ready AND B buf0 ready

    // ---------------- Phase 1: logits = x @ Wp^T (dbuf DMA, counted vmcnt) ----------------
    f32x4 acc1[2][10];
    const f32x4 fz = {0.f, 0.f, 0.f, 0.f};
#pragma unroll
    for (int rt = 0; rt < 2; ++rt)
#pragma unroll
        for (int ct = 0; ct < 10; ++ct) acc1[rt][ct] = fz;

    const int aB = (wr * 32 + ln) * 1024;                  // + rt*16384
    const int bB = (wc * 160 + ln) * 64 + qswz;            // + ct*1024 within a B buffer

#pragma unroll 2
    for (int ks = 0; ks < 16; ++ks) {
        const int cur = ks & 1;
        if (ks < 15) {
            const unsigned short* gk = WpB + (ks + 1) * 32;
            char* lb = smem + B_OFF + (cur ^ 1) * B_BUF;
#pragma unroll
            for (int i = 0; i < 5; ++i)
                gl2lds16(gk + bgo[i], lb + (i * TPB + tid) * 16);
            asm volatile("s_waitcnt vmcnt(5)" ::: "memory");   // buf[cur]'s 5 landed; 5 stay in flight
        } else {
            asm volatile("s_waitcnt vmcnt(0)" ::: "memory");
        }
        asm volatile("s_barrier" ::: "memory");                // buf[cur] visible to all waves

        const int at = (ks * 64 + q * 16) ^ swz;
        bf16x8 af0 = *(const bf16x8*)(smem + aB + at);
        bf16x8 af1 = *(const bf16x8*)(smem + aB + 16384 + at);
        bf16x8 bfr[10];
        const char* bsrc = smem + B_OFF + cur * B_BUF + bB;
#pragma unroll
        for (int ct = 0; ct < 10; ++ct)
            bfr[ct] = *(const bf16x8*)(bsrc + ct * 1024);
        asm volatile("s_waitcnt lgkmcnt(0)" ::: "memory");
        __builtin_amdgcn_sched_barrier(0);
        asm volatile("s_barrier" ::: "memory");                // reads done -> buf[cur] reusable

        __builtin_amdgcn_s_setprio(1);
#pragma unroll
        for (int ct = 0; ct < 10; ++ct) {
            acc1[0][ct] = __builtin_amdgcn_mfma_f32_16x16x32_bf16(af0, bfr[ct], acc1[0][ct], 0, 0, 0);
            acc1[1][ct] = __builtin_amdgcn_mfma_f32_16x16x32_bf16(af1, bfr[ct], acc1[1][ct], 0, 0, 0);
        }
        __builtin_amdgcn_s_setprio(0);
    }
    __syncthreads();   // phase-1 LDS fully dead

    // Prefetch cb buf0 DMA now — overlaps with all of phase 2.
#pragma unroll
    for (int i = 0; i < 4; ++i)
        gl2lds16(cbT + cgo[i], smem + CB_OFF + (i * TPB + tid) * 16);

    // ---------------- Phase 2: exp + row sums; y -> LDS (swizzled) ----------------
    float bpv[10];
#pragma unroll
    for (int ct = 0; ct < 10; ++ct) bpv[ct] = bpv_g[wc * 160 + ct * 16 + ln];

    const float* gbase = gum + (size_t)(rowbase + wr * 32) * NE + wc * 160 + ln;
    float gv[10];
    {
        const float* p0 = gbase + (size_t)(q * 4) * NE;
#pragma unroll
        for (int ct = 0; ct < 10; ++ct) gv[ct] = p0[ct * 16];
    }
#pragma unroll
    for (int ri = 0; ri < 8; ++ri) {
        float gn[10];
        if (ri < 7) {
            int nrow = ((ri + 1) >> 2) * 16 + q * 4 + ((ri + 1) & 3);
            const float* pn = gbase + (size_t)nrow * NE;
#pragma unroll
            for (int ct = 0; ct < 10; ++ct) gn[ct] = pn[ct * 16];
        }
        int rt = ri >> 2, r = ri & 3;
        int lrow = wr * 32 + rt * 16 + q * 4 + r;
        int ybase = lrow * 1280;
        int yswz  = (lrow & 7) << 4;
        float p = 0.f;
#pragma unroll
        for (int ct = 0; ct < 10; ++ct) {
            int col = wc * 160 + ct * 16 + ln;
            float v = acc1[rt][ct][r] + bpv[ct] + gv[ct];
            float e = __expf(v);
            *(unsigned short*)(smem + ybase + ((col * 2) ^ yswz)) = f2b(e);
            p += e;
        }
        p += __shfl_xor(p, 1);
        p += __shfl_xor(p, 2);
        p += __shfl_xor(p, 4);
        p += __shfl_xor(p, 8);
        if (ln == 0) atomicAdd(&sS[lrow], p);
#pragma unroll
        for (int ct = 0; ct < 10; ++ct) gv[ct] = gn[ct];
    }
    __syncthreads();   // y + S complete; cb buf0 DMA also drained here

    // ---------------- Phase 3: out = (y @ cb) / S (dbuf DMA, counted vmcnt) ----------------
    f32x4 acc2[2][8];
#pragma unroll
    for (int rt = 0; rt < 2; ++rt)
#pragma unroll
        for (int ct = 0; ct < 8; ++ct) acc2[rt][ct] = fz;

    const int g  = wc >> 1;          // group
    const int nb = (wc & 1) * 128;   // col block within group
    const int yB = (wr * 32 + ln) * 1280;                    // + rt*20480
    const int cB = (g * 256 + nb + ln) * 64 + qswz;          // + ct*1024 within a cb buffer

#pragma unroll 2
    for (int ks = 0; ks < 10; ++ks) {
        const int cur = ks & 1;
        if (ks < 9) {
            const unsigned short* gk = cbT + (ks + 1) * 32;
            char* lb = smem + CB_OFF + (cur ^ 1) * CB_BUF;
#pragma unroll
            for (int i = 0; i < 4; ++i)
                gl2lds16(gk + cgo[i], lb + (i * TPB + tid) * 16);
            asm volatile("s_waitcnt vmcnt(4)" ::: "memory");
        } else {
            asm volatile("s_waitcnt vmcnt(0)" ::: "memory");
        }
        asm volatile("s_barrier" ::: "memory");

        const int at = (g * 640 + ks * 64 + q * 16) ^ swz;
        bf16x8 af0 = *(const bf16x8*)(smem + yB + at);
        bf16x8 af1 = *(const bf16x8*)(smem + yB + 20480 + at);
        bf16x8 bfr[8];
        const char* csrc = smem + CB_OFF + cur * CB_BUF + cB;
#pragma unroll
        for (int ct = 0; ct < 8; ++ct)
            bfr[ct] = *(const bf16x8*)(csrc + ct * 1024);
        asm volatile("s_waitcnt lgkmcnt(0)" ::: "memory");
        __builtin_amdgcn_sched_barrier(0);
        asm volatile("s_barrier" ::: "memory");

        __builtin_amdgcn_s_setprio(1);
#pragma unroll
        for (int ct = 0; ct < 8; ++ct) {
            acc2[0][ct] = __builtin_amdgcn_mfma_f32_16x16x32_bf16(af0, bfr[ct], acc2[0][ct], 0, 0, 0);
            acc2[1][ct] = __builtin_amdgcn_mfma_f32_16x16x32_bf16(af1, bfr[ct], acc2[1][ct], 0, 0, 0);
        }
        __builtin_amdgcn_s_setprio(0);
    }

    // epilogue: divide by softmax denom, store fp32
#pragma unroll
    for (int rt = 0; rt < 2; ++rt) {
#pragma unroll
        for (int r = 0; r < 4; ++r) {
            int lrow = wr * 32 + rt * 16 + q * 4 + r;
            float inv = 1.0f / sS[lrow];
            size_t orow = (size_t)(rowbase + lrow) * 512;
#pragma unroll
            for (int ct = 0; ct < 8; ++ct) {
                int col = g * 256 + nb + ct * 16 + ln;
                out[orow + col] = acc2[rt][ct][r] * inv;
            }
        }
    }
}

extern "C" void kernel_launch(void* const* d_in, const int* in_sizes, int n_in,
                              void* d_out, int out_size, void* d_ws, size_t ws_size,
                              hipStream_t stream) {
    const float* x   = (const float*)d_in[0];
    const float* Wp  = (const float*)d_in[1];
    const float* bp  = (const float*)d_in[2];
    const float* cb  = (const float*)d_in[3];
    const float* gum = (const float*)d_in[4];
    float* out = (float*)d_out;

    unsigned short* WpB = (unsigned short*)d_ws;
    unsigned short* cbT = WpB + NE * CIN;

    int prep_total = NE * CIN + 2 * ENTRY * DD;
    prep_kernel<<<(prep_total + 255) / 256, 256, 0, stream>>>(Wp, cb, WpB, cbT);

    fused_kernel<<<dim3(BT / MROWS), dim3(TPB), SMEM_BYTES, stream>>>(x, bp, gum, WpB, cbT, out);
}